// Round 13
// baseline (308.239 us; speedup 1.0000x reference)
//
#include <hip/hip_runtime.h>
#include <hip/hip_bf16.h>

// Swin block: B=32, HW=56, C=128, WS=7, SS=3, NH=4, HD=32
#define NTOK 100352
#define SCALE_Q 0.17677669529663687f  // 32^-0.5

typedef __bf16 bf16x8 __attribute__((ext_vector_type(8)));
typedef float f32x4 __attribute__((ext_vector_type(4)));
struct bf2 { __hip_bfloat16 x, y; };

// window-token (wt = w*49+n) -> original flat token index in x
__device__ __forceinline__ int wt_to_tok(int wt) {
  int w = wt / 49, n = wt - w * 49;
  int b = w >> 6, wi = w & 63;
  int gh = wi >> 3, gw = wi & 7;
  int r = n / 7, c = n - r * 7;
  int hs = gh * 7 + r + 3; if (hs >= 56) hs -= 56;   // undo roll(-3)
  int ws = gw * 7 + c + 3; if (ws >= 56) ws -= 56;
  return (b * 56 + hs) * 56 + ws;
}

// sigmoid-approx GELU: v * sigmoid(1.702 v)
__device__ __forceinline__ float gelu_sig(float v) {
  return v / (1.0f + __expf(-1.702f * v));
}

// all weight transposes + bf16 in one launch
__global__ __launch_bounds__(256) void prep_all(const float* __restrict__ qkvw,
                                                const float* __restrict__ projw,
                                                const float* __restrict__ w1,
                                                const float* __restrict__ w2,
                                                __hip_bfloat16* __restrict__ dst) {
  int i = blockIdx.x * 256 + threadIdx.x;
  float v;
  if (i < 49152) { int n = i >> 7, k = i & 127; v = qkvw[k * 384 + n]; }
  else if (i < 65536) { int j = i - 49152; int n = j >> 7, k = j & 127; v = projw[k * 128 + n]; }
  else if (i < 131072) { int j = i - 65536; int n = j >> 7, k = j & 127; v = w1[k * 512 + n]; }
  else { int j = i - 131072; int n = j / 512, k = j - n * 512; v = w2[k * 128 + n]; }
  dst[i] = __float2bfloat16(v);
}

// xn[wt] = bf16(LN1(x[tok])) — gather to window order fused
__global__ __launch_bounds__(256) void ln1_apply(const float* __restrict__ x,
                                                 const float* __restrict__ nw,
                                                 const float* __restrict__ nb,
                                                 __hip_bfloat16* __restrict__ xn) {
  int wt = blockIdx.x * 4 + (threadIdx.x >> 6);
  int lane = threadIdx.x & 63;
  int tok = wt_to_tok(wt);
  float2 v = *(const float2*)(x + (size_t)tok * 128 + lane * 2);
  float s = v.x + v.y, ss = v.x * v.x + v.y * v.y;
#pragma unroll
  for (int off = 32; off; off >>= 1) {
    s += __shfl_xor(s, off);
    ss += __shfl_xor(ss, off);
  }
  float mu = s * (1.0f / 128.0f);
  float rstd = rsqrtf(ss * (1.0f / 128.0f) - mu * mu + 1e-5f);
  float2 wv = *(const float2*)(nw + lane * 2);
  float2 bv = *(const float2*)(nb + lane * 2);
  bf2 o;
  o.x = __float2bfloat16((v.x - mu) * rstd * wv.x + bv.x);
  o.y = __float2bfloat16((v.y - mu) * rstd * wv.y + bv.y);
  *(bf2*)(xn + (size_t)wt * 128 + lane * 2) = o;
}

// ---------------------------------------------------------------------------
// MFMA attention (unchanged): 1 block = 1 window, wave h = head h.
// ---------------------------------------------------------------------------
__global__ __launch_bounds__(256) void attn_mfma(const __hip_bfloat16* __restrict__ qkv,
                                                 const float* __restrict__ ptab,
                                                 __hip_bfloat16* __restrict__ attnout) {
  __shared__ __align__(16) char lds[4 * 12288];
  const int tid = threadIdx.x;
  const int lane = tid & 63, h = tid >> 6;
  const int w = blockIdx.x;
  const int wi = w & 63, gh = wi >> 3, gw = wi & 7;
  char* Pl = lds + h * 12288;
  char* VTl = Pl + 8192;
  const int lxi = lane & 15, lq = lane >> 4, lg4 = (lane >> 4) * 4;

  const __hip_bfloat16* base = qkv + (size_t)w * 49 * 384 + h * 32;
  __hip_bfloat16* op = attnout + (size_t)w * 49 * 128 + h * 32;

  bf16x8 qa[4], kb[4];
#pragma unroll
  for (int mi = 0; mi < 4; ++mi) {
    int t = mi * 16 + lxi; if (t > 48) t = 48;
    qa[mi] = *(const bf16x8*)(base + (size_t)t * 384 + lq * 8);
    kb[mi] = *(const bf16x8*)(base + (size_t)t * 384 + 128 + lq * 8);
  }
  {
    union { bf16x8 v; __hip_bfloat16 e[8]; } vv[4];
    const __hip_bfloat16* vp = base + (size_t)(lane < 49 ? lane : 0) * 384 + 256;
#pragma unroll
    for (int q = 0; q < 4; ++q) vv[q].v = *(const bf16x8*)(vp + q * 8);
    __hip_bfloat16 z = __float2bfloat16(0.0f);
#pragma unroll
    for (int q = 0; q < 4; ++q)
#pragma unroll
      for (int e = 0; e < 8; ++e) {
        int d = q * 8 + e;
        __hip_bfloat16 val = (lane < 49) ? vv[q].e[e] : z;
        *(__hip_bfloat16*)(VTl + d * 128 + ((lane * 2) ^ ((d & 7) << 4))) = val;
      }
  }

  f32x4 s[4][4] = {};
#pragma unroll
  for (int mi = 0; mi < 4; ++mi)
#pragma unroll
    for (int ni = 0; ni < 4; ++ni)
      s[mi][ni] = __builtin_amdgcn_mfma_f32_16x16x32_bf16(qa[mi], kb[ni], s[mi][ni], 0, 0, 0);

  int rj[4], cj[4], cntj[4], jbad[4];
#pragma unroll
  for (int ni = 0; ni < 4; ++ni) {
    int jc = ni * 16 + lxi;
    jbad[ni] = (jc > 48);
    int jj = jbad[ni] ? 48 : jc;
    rj[ni] = jj / 7; cj[ni] = jj - rj[ni] * 7;
    int hj = gh * 7 + rj[ni], wj = gw * 7 + cj[ni];
    cntj[ni] = (hj < 49 ? 0 : (hj < 53 ? 3 : 6)) + (wj < 49 ? 0 : (wj < 53 ? 1 : 2));
  }
#pragma unroll
  for (int mi = 0; mi < 4; ++mi)
#pragma unroll
    for (int j = 0; j < 4; ++j) {
      int i = mi * 16 + lg4 + j; if (i > 48) i = 48;
      int ri = i / 7, ci = i - ri * 7;
      int hi_ = gh * 7 + ri, wi_ = gw * 7 + ci;
      int cnti = (hi_ < 49 ? 0 : (hi_ < 53 ? 3 : 6)) + (wi_ < 49 ? 0 : (wi_ < 53 ? 1 : 2));
#pragma unroll
      for (int ni = 0; ni < 4; ++ni) {
        float b = ptab[((ri - rj[ni] + 6) * 13 + (ci - cj[ni] + 6)) * 4 + h];
        float val = s[mi][ni][j] * SCALE_Q + b;
        if (cnti != cntj[ni]) val -= 100.0f;
        if (jbad[ni]) val = -1e30f;
        s[mi][ni][j] = val;
      }
    }

#pragma unroll
  for (int mi = 0; mi < 4; ++mi)
#pragma unroll
    for (int j = 0; j < 4; ++j) {
      float m = fmaxf(fmaxf(s[mi][0][j], s[mi][1][j]), fmaxf(s[mi][2][j], s[mi][3][j]));
#pragma unroll
      for (int off = 8; off; off >>= 1) m = fmaxf(m, __shfl_xor(m, off));
      float e[4], sum = 0.0f;
#pragma unroll
      for (int ni = 0; ni < 4; ++ni) { e[ni] = __expf(s[mi][ni][j] - m); sum += e[ni]; }
#pragma unroll
      for (int off = 8; off; off >>= 1) sum += __shfl_xor(sum, off);
      float inv = 1.0f / sum;
#pragma unroll
      for (int ni = 0; ni < 4; ++ni) s[mi][ni][j] = e[ni] * inv;
    }

#pragma unroll
  for (int mi = 0; mi < 4; ++mi)
#pragma unroll
    for (int j = 0; j < 4; ++j) {
      int row = mi * 16 + lg4 + j;
      int sw = (row & 7) << 4;
      char* prow = Pl + row * 128;
#pragma unroll
      for (int ni = 0; ni < 4; ++ni)
        *(__hip_bfloat16*)(prow + (((ni * 16 + lxi) * 2) ^ sw)) =
            __float2bfloat16(s[mi][ni][j]);
    }

  __syncthreads();

  f32x4 o[4][2] = {};
#pragma unroll
  for (int ks = 0; ks < 2; ++ks) {
    bf16x8 pa[4], vb[2];
#pragma unroll
    for (int mi = 0; mi < 4; ++mi) {
      int row = mi * 16 + lxi;
      pa[mi] = *(const bf16x8*)(Pl + row * 128 + ((ks * 64 + lq * 16) ^ ((row & 7) << 4)));
    }
#pragma unroll
    for (int ni = 0; ni < 2; ++ni) {
      int row = ni * 16 + lxi;
      vb[ni] = *(const bf16x8*)(VTl + row * 128 + ((ks * 64 + lq * 16) ^ ((row & 7) << 4)));
    }
#pragma unroll
    for (int mi = 0; mi < 4; ++mi)
#pragma unroll
      for (int ni = 0; ni < 2; ++ni)
        o[mi][ni] = __builtin_amdgcn_mfma_f32_16x16x32_bf16(pa[mi], vb[ni], o[mi][ni], 0, 0, 0);
  }

#pragma unroll
  for (int mi = 0; mi < 4; ++mi)
#pragma unroll
    for (int j = 0; j < 4; ++j) {
      int q = mi * 16 + lg4 + j;
      if (q < 49) {
#pragma unroll
        for (int ni = 0; ni < 2; ++ni)
          op[(size_t)q * 128 + ni * 16 + lxi] = __float2bfloat16(o[mi][ni][j]);
      }
    }
}

// ---------------------------------------------------------------------------
// MFMA bf16 GEMM with N-LOOP prologue amortization (r11 layout, acc[mi][ni]).
// NCHUNK>1 (requires K==128): block owns an M-panel; A staged in LDS ONCE,
//   then loops over NCHUNK column chunks with ZERO barriers in the loop
//   (LDS read-only; B-frags stream from L2; chunk n+1 loads overlap chunk n
//   MFMAs). Amortizes stage+barrier 3-4x.
// NCHUNK==1: r11's K-loop path (proj EPI4, mlp2 EPI3 K=512).
// EPI: 0 = +bias -> bf16(ldo);  1 = gelu_sig(+bias) -> bf16(ldo)
//      3 = +bias +resb(bf16) -> fp32 out (stride 128)
//      4 = proj+LN2 fused: x2[tok]=bf16(acc+bias+resf[tok]);
//          out2[tok]=bf16(LN(row)*nw+nb)
// ---------------------------------------------------------------------------
template<int NCHUNK, int K, int EPI>
__global__ __launch_bounds__(256) void gemm_nloop(
    const __hip_bfloat16* __restrict__ A, int lda,
    const __hip_bfloat16* __restrict__ Wt,
    const float* __restrict__ bias,
    void* __restrict__ outv, int ldo,
    __hip_bfloat16* __restrict__ out2,
    const float* __restrict__ nw, const float* __restrict__ nb,
    const float* __restrict__ resf, const __hip_bfloat16* __restrict__ resb)
{
  __shared__ __align__(16) char AsB[128 * 256];
  __shared__ float redS[256], redQ[256];
  const int m0 = blockIdx.x * 128;
  const int tid = threadIdx.x;
  const int srow = tid >> 1;
  const int scol = (tid & 1) * 64;
  const int lane = tid & 63, wid = tid >> 6;
  const int wm = wid >> 1, wn = wid & 1;
  const int lrow = lane & 15, lq = lane >> 4;

  if (NCHUNK > 1) {
    // ---- stage A once (K == 128) ----
    {
      const char* ap = (const char*)A + ((size_t)(m0 + srow) * lda + scol) * 2;
      char* dst = AsB + srow * 256;
      int sw = (srow & 7) << 4;
#pragma unroll
      for (int t = 0; t < 8; ++t) {
        int4 raw = *(const int4*)(ap + t * 16);
        *(int4*)(dst + ((scol * 2 + t * 16) ^ sw)) = raw;
      }
    }
    __syncthreads();

    for (int nc = 0; nc < NCHUNK; ++nc) {
      const int n0 = nc * 128;
      f32x4 acc[4][4] = {};
#pragma unroll
      for (int ks = 0; ks < 4; ++ks) {
        int kb = ks * 64 + lq * 16;
        bf16x8 af[4], bfr[4];
#pragma unroll
        for (int mi = 0; mi < 4; ++mi) {
          int r = wm * 64 + mi * 16 + lrow;
          af[mi] = *(const bf16x8*)(AsB + r * 256 + (kb ^ ((r & 7) << 4)));
        }
#pragma unroll
        for (int ni = 0; ni < 4; ++ni) {
          int n = n0 + wn * 64 + ni * 16 + lrow;
          bfr[ni] = *(const bf16x8*)(Wt + (size_t)n * 128 + ks * 32 + lq * 8);
        }
#pragma unroll
        for (int mi = 0; mi < 4; ++mi)
#pragma unroll
          for (int ni = 0; ni < 4; ++ni)
            acc[mi][ni] = __builtin_amdgcn_mfma_f32_16x16x32_bf16(af[mi], bfr[ni], acc[mi][ni], 0, 0, 0);
      }
      float bv[4];
#pragma unroll
      for (int ni = 0; ni < 4; ++ni) bv[ni] = bias[n0 + wn * 64 + ni * 16 + lrow];
#pragma unroll
      for (int mi = 0; mi < 4; ++mi) {
#pragma unroll
        for (int j = 0; j < 4; ++j) {
          int rowg = m0 + wm * 64 + mi * 16 + lq * 4 + j;
#pragma unroll
          for (int ni = 0; ni < 4; ++ni) {
            int colg = n0 + wn * 64 + ni * 16 + lrow;
            float val = acc[mi][ni][j] + bv[ni];
            if (EPI == 1) val = gelu_sig(val);
            ((__hip_bfloat16*)outv)[(size_t)rowg * ldo + colg] = __float2bfloat16(val);
          }
        }
      }
    }
    return;
  }

  // ---- NCHUNK == 1: r11 K-loop path ----
  f32x4 acc[4][4] = {};
  for (int k0 = 0; k0 < K; k0 += 128) {
    {
      const char* ap = (const char*)A + ((size_t)(m0 + srow) * lda + k0 + scol) * 2;
      char* dst = AsB + srow * 256;
      int sw = (srow & 7) << 4;
#pragma unroll
      for (int t = 0; t < 8; ++t) {
        int4 raw = *(const int4*)(ap + t * 16);
        *(int4*)(dst + ((scol * 2 + t * 16) ^ sw)) = raw;
      }
    }
    __syncthreads();
#pragma unroll
    for (int ks = 0; ks < 4; ++ks) {
      int kb = ks * 64 + lq * 16;
      bf16x8 af[4], bfr[4];
#pragma unroll
      for (int mi = 0; mi < 4; ++mi) {
        int r = wm * 64 + mi * 16 + lrow;
        af[mi] = *(const bf16x8*)(AsB + r * 256 + (kb ^ ((r & 7) << 4)));
      }
#pragma unroll
      for (int ni = 0; ni < 4; ++ni) {
        int n = wn * 64 + ni * 16 + lrow;
        bfr[ni] = *(const bf16x8*)(Wt + (size_t)n * K + k0 + ks * 32 + lq * 8);
      }
#pragma unroll
      for (int mi = 0; mi < 4; ++mi)
#pragma unroll
        for (int ni = 0; ni < 4; ++ni)
          acc[mi][ni] = __builtin_amdgcn_mfma_f32_16x16x32_bf16(af[mi], bfr[ni], acc[mi][ni], 0, 0, 0);
    }
    __syncthreads();
  }

  float bv[4];
#pragma unroll
  for (int ni = 0; ni < 4; ++ni) bv[ni] = bias[wn * 64 + ni * 16 + lrow];

  if (EPI == 4) {
    // proj + residual + LN2 fused. Block owns full 128-wide rows.
    __hip_bfloat16* x2 = (__hip_bfloat16*)outv;
    float nwc[4], nbc[4];
#pragma unroll
    for (int ni = 0; ni < 4; ++ni) {
      int colg = wn * 64 + ni * 16 + lrow;
      nwc[ni] = nw[colg]; nbc[ni] = nb[colg];
    }
    int toks[4][4];
#pragma unroll
    for (int mi = 0; mi < 4; ++mi)
#pragma unroll
      for (int j = 0; j < 4; ++j) {
        int row = wm * 64 + mi * 16 + lq * 4 + j;
        int tok = wt_to_tok(m0 + row);
        toks[mi][j] = tok;
        float s = 0.0f, ss = 0.0f;
#pragma unroll
        for (int ni = 0; ni < 4; ++ni) {
          int colg = wn * 64 + ni * 16 + lrow;
          float val = acc[mi][ni][j] + bv[ni] + resf[(size_t)tok * 128 + colg];
          x2[(size_t)tok * 128 + colg] = __float2bfloat16(val);
          acc[mi][ni][j] = val;
          s += val; ss += val * val;
        }
#pragma unroll
        for (int off = 8; off; off >>= 1) {
          s += __shfl_xor(s, off);
          ss += __shfl_xor(ss, off);
        }
        if (lrow == 0) { redS[row * 2 + wn] = s; redQ[row * 2 + wn] = ss; }
      }
    __syncthreads();
#pragma unroll
    for (int mi = 0; mi < 4; ++mi)
#pragma unroll
      for (int j = 0; j < 4; ++j) {
        int row = wm * 64 + mi * 16 + lq * 4 + j;
        float s = redS[row * 2] + redS[row * 2 + 1];
        float ss = redQ[row * 2] + redQ[row * 2 + 1];
        float mu = s * (1.0f / 128.0f);
        float rstd = rsqrtf(ss * (1.0f / 128.0f) - mu * mu + 1e-5f);
        int tok = toks[mi][j];
#pragma unroll
        for (int ni = 0; ni < 4; ++ni) {
          int colg = wn * 64 + ni * 16 + lrow;
          float xnv = (acc[mi][ni][j] - mu) * rstd * nwc[ni] + nbc[ni];
          out2[(size_t)tok * 128 + colg] = __float2bfloat16(xnv);
        }
      }
    return;
  }

  // EPI == 3
#pragma unroll
  for (int mi = 0; mi < 4; ++mi) {
#pragma unroll
    for (int j = 0; j < 4; ++j) {
      int rowg = m0 + wm * 64 + mi * 16 + lq * 4 + j;
#pragma unroll
      for (int ni = 0; ni < 4; ++ni) {
        int colg = wn * 64 + ni * 16 + lrow;
        float val = acc[mi][ni][j] + bv[ni];
        float r = __bfloat162float(resb[(size_t)rowg * 128 + colg]);
        ((float*)outv)[(size_t)rowg * 128 + colg] = val + r;
      }
    }
  }
}

extern "C" void kernel_launch(void* const* d_in, const int* in_sizes, int n_in,
                              void* d_out, int out_size, void* d_ws, size_t ws_size,
                              hipStream_t stream) {
  (void)in_sizes; (void)n_in; (void)out_size; (void)ws_size;
  const float* x     = (const float*)d_in[0];
  const float* n1w   = (const float*)d_in[1];
  const float* n1b   = (const float*)d_in[2];
  const float* qkvw  = (const float*)d_in[3];
  const float* qkvb  = (const float*)d_in[4];
  const float* projw = (const float*)d_in[5];
  const float* projb = (const float*)d_in[6];
  const float* ptab  = (const float*)d_in[7];
  const float* w1    = (const float*)d_in[8];
  const float* b1    = (const float*)d_in[9];
  const float* w2    = (const float*)d_in[10];
  const float* b2    = (const float*)d_in[11];
  const float* n2w   = (const float*)d_in[12];
  const float* n2b   = (const float*)d_in[13];
  float* out = (float*)d_out;

  // workspace layout (bytes):
  //   [0,          25690112)   xn   bf16 [wt][128]  (LN1, window order)
  //   [25690112,  102760448)   qkv  bf16 [wt][384]
  //   [102760448, 128450560)   attnout bf16 [wt][128]
  //     u bf16 [tok][512] aliases [25690112, 128450560) (qkv+attnout dead)
  //   [128450560, 154140672)   x2   bf16 [tok][128]  (residual stream)
  //   [154140672, 179830784)   x2n  bf16 [tok][128]  (LN2 applied)
  //   [179830784, 180224000)   transposed bf16 weights
  char* ws = (char*)d_ws;
  __hip_bfloat16* xn      = (__hip_bfloat16*)ws;
  __hip_bfloat16* qkv     = (__hip_bfloat16*)(ws + 25690112);
  __hip_bfloat16* attnout = (__hip_bfloat16*)(ws + 102760448);
  __hip_bfloat16* u       = (__hip_bfloat16*)(ws + 25690112);
  __hip_bfloat16* x2      = (__hip_bfloat16*)(ws + 128450560);
  __hip_bfloat16* x2n     = (__hip_bfloat16*)(ws + 154140672);
  __hip_bfloat16* wbase   = (__hip_bfloat16*)(ws + 179830784);
  __hip_bfloat16* qkvwT  = wbase;            // [384][128]
  __hip_bfloat16* projwT = wbase + 49152;    // [128][128]
  __hip_bfloat16* w1T    = wbase + 65536;    // [512][128]
  __hip_bfloat16* w2T    = wbase + 131072;   // [128][512]

  prep_all<<<768, 256, 0, stream>>>(qkvw, projw, w1, w2, wbase);
  ln1_apply<<<NTOK / 4, 256, 0, stream>>>(x, n1w, n1b, xn);
  // qkv = xn @ qkv_w + qkv_b : N-loop over 3 chunks, A staged once
  gemm_nloop<3, 128, 0><<<784, 256, 0, stream>>>(xn, 128, qkvwT, qkvb,
                                                 qkv, 384, nullptr, nullptr, nullptr,
                                                 nullptr, nullptr);
  attn_mfma<<<2048, 256, 0, stream>>>(qkv, ptab, attnout);
  // proj: x2[tok]=bf16(x+attnout@projW+b); x2n=bf16(LN2(row))
  gemm_nloop<1, 128, 4><<<784, 256, 0, stream>>>(attnout, 128, projwT, projb,
                                                 x2, 128, x2n, n2w, n2b, x, nullptr);
  // mlp1: u = gelu_sig(x2n @ w1 + b1) : N-loop over 4 chunks, A staged once
  gemm_nloop<4, 128, 1><<<784, 256, 0, stream>>>(x2n, 128, w1T, b1,
                                                 (void*)u, 512, nullptr, nullptr, nullptr,
                                                 nullptr, nullptr);
  // mlp2: out = x2 + u @ w2 + b2 : K=512
  gemm_nloop<1, 512, 3><<<784, 256, 0, stream>>>(u, 512, w2T, b2,
                                                 out, 128, nullptr, nullptr, nullptr,
                                                 nullptr, x2);
}

// Round 14
// 237.571 us; speedup vs baseline: 1.2975x; 1.2975x over previous
//
#include <hip/hip_runtime.h>
#include <hip/hip_bf16.h>

// Swin block: B=32, HW=56, C=128, WS=7, SS=3, NH=4, HD=32
#define NTOK 100352
#define SCALE_Q 0.17677669529663687f  // 32^-0.5

typedef __bf16 bf16x8 __attribute__((ext_vector_type(8)));
typedef float f32x4 __attribute__((ext_vector_type(4)));
struct bf2 { __hip_bfloat16 x, y; };
struct __align__(8) bh4 { __hip_bfloat16 a, b, c, d; };

// window-token (wt = w*49+n) -> original flat token index in x
__device__ __forceinline__ int wt_to_tok(int wt) {
  int w = wt / 49, n = wt - w * 49;
  int b = w >> 6, wi = w & 63;
  int gh = wi >> 3, gw = wi & 7;
  int r = n / 7, c = n - r * 7;
  int hs = gh * 7 + r + 3; if (hs >= 56) hs -= 56;   // undo roll(-3)
  int ws = gw * 7 + c + 3; if (ws >= 56) ws -= 56;
  return (b * 56 + hs) * 56 + ws;
}

// sigmoid-approx GELU: v * sigmoid(1.702 v) — ~5 VALU ops
__device__ __forceinline__ float gelu_sig(float v) {
  return v / (1.0f + __expf(-1.702f * v));
}

// all weight transposes + bf16 in one launch
__global__ __launch_bounds__(256) void prep_all(const float* __restrict__ qkvw,
                                                const float* __restrict__ projw,
                                                const float* __restrict__ w1,
                                                const float* __restrict__ w2,
                                                __hip_bfloat16* __restrict__ dst) {
  int i = blockIdx.x * 256 + threadIdx.x;
  float v;
  if (i < 49152) { int n = i >> 7, k = i & 127; v = qkvw[k * 384 + n]; }
  else if (i < 65536) { int j = i - 49152; int n = j >> 7, k = j & 127; v = projw[k * 128 + n]; }
  else if (i < 131072) { int j = i - 65536; int n = j >> 7, k = j & 127; v = w1[k * 512 + n]; }
  else { int j = i - 131072; int n = j / 512, k = j - n * 512; v = w2[k * 128 + n]; }
  dst[i] = __float2bfloat16(v);
}

// xn[wt] = bf16(LN1(x[tok])) — gather to window order fused
__global__ __launch_bounds__(256) void ln1_apply(const float* __restrict__ x,
                                                 const float* __restrict__ nw,
                                                 const float* __restrict__ nb,
                                                 __hip_bfloat16* __restrict__ xn) {
  int wt = blockIdx.x * 4 + (threadIdx.x >> 6);
  int lane = threadIdx.x & 63;
  int tok = wt_to_tok(wt);
  float2 v = *(const float2*)(x + (size_t)tok * 128 + lane * 2);
  float s = v.x + v.y, ss = v.x * v.x + v.y * v.y;
#pragma unroll
  for (int off = 32; off; off >>= 1) {
    s += __shfl_xor(s, off);
    ss += __shfl_xor(ss, off);
  }
  float mu = s * (1.0f / 128.0f);
  float rstd = rsqrtf(ss * (1.0f / 128.0f) - mu * mu + 1e-5f);
  float2 wv = *(const float2*)(nw + lane * 2);
  float2 bv = *(const float2*)(nb + lane * 2);
  bf2 o;
  o.x = __float2bfloat16((v.x - mu) * rstd * wv.x + bv.x);
  o.y = __float2bfloat16((v.y - mu) * rstd * wv.y + bv.y);
  *(bf2*)(xn + (size_t)wt * 128 + lane * 2) = o;
}

// ---------------------------------------------------------------------------
// MFMA attention: 1 block = 1 window, wave h = head h.
// ---------------------------------------------------------------------------
__global__ __launch_bounds__(256) void attn_mfma(const __hip_bfloat16* __restrict__ qkv,
                                                 const float* __restrict__ ptab,
                                                 __hip_bfloat16* __restrict__ attnout) {
  __shared__ __align__(16) char lds[4 * 12288];
  const int tid = threadIdx.x;
  const int lane = tid & 63, h = tid >> 6;
  const int w = blockIdx.x;
  const int wi = w & 63, gh = wi >> 3, gw = wi & 7;
  char* Pl = lds + h * 12288;
  char* VTl = Pl + 8192;
  const int lxi = lane & 15, lq = lane >> 4, lg4 = (lane >> 4) * 4;

  const __hip_bfloat16* base = qkv + (size_t)w * 49 * 384 + h * 32;
  __hip_bfloat16* op = attnout + (size_t)w * 49 * 128 + h * 32;

  bf16x8 qa[4], kb[4];
#pragma unroll
  for (int mi = 0; mi < 4; ++mi) {
    int t = mi * 16 + lxi; if (t > 48) t = 48;
    qa[mi] = *(const bf16x8*)(base + (size_t)t * 384 + lq * 8);
    kb[mi] = *(const bf16x8*)(base + (size_t)t * 384 + 128 + lq * 8);
  }
  {
    union { bf16x8 v; __hip_bfloat16 e[8]; } vv[4];
    const __hip_bfloat16* vp = base + (size_t)(lane < 49 ? lane : 0) * 384 + 256;
#pragma unroll
    for (int q = 0; q < 4; ++q) vv[q].v = *(const bf16x8*)(vp + q * 8);
    __hip_bfloat16 z = __float2bfloat16(0.0f);
#pragma unroll
    for (int q = 0; q < 4; ++q)
#pragma unroll
      for (int e = 0; e < 8; ++e) {
        int d = q * 8 + e;
        __hip_bfloat16 val = (lane < 49) ? vv[q].e[e] : z;
        *(__hip_bfloat16*)(VTl + d * 128 + ((lane * 2) ^ ((d & 7) << 4))) = val;
      }
  }

  f32x4 s[4][4] = {};
#pragma unroll
  for (int mi = 0; mi < 4; ++mi)
#pragma unroll
    for (int ni = 0; ni < 4; ++ni)
      s[mi][ni] = __builtin_amdgcn_mfma_f32_16x16x32_bf16(qa[mi], kb[ni], s[mi][ni], 0, 0, 0);

  int rj[4], cj[4], cntj[4], jbad[4];
#pragma unroll
  for (int ni = 0; ni < 4; ++ni) {
    int jc = ni * 16 + lxi;
    jbad[ni] = (jc > 48);
    int jj = jbad[ni] ? 48 : jc;
    rj[ni] = jj / 7; cj[ni] = jj - rj[ni] * 7;
    int hj = gh * 7 + rj[ni], wj = gw * 7 + cj[ni];
    cntj[ni] = (hj < 49 ? 0 : (hj < 53 ? 3 : 6)) + (wj < 49 ? 0 : (wj < 53 ? 1 : 2));
  }
#pragma unroll
  for (int mi = 0; mi < 4; ++mi)
#pragma unroll
    for (int j = 0; j < 4; ++j) {
      int i = mi * 16 + lg4 + j; if (i > 48) i = 48;
      int ri = i / 7, ci = i - ri * 7;
      int hi_ = gh * 7 + ri, wi_ = gw * 7 + ci;
      int cnti = (hi_ < 49 ? 0 : (hi_ < 53 ? 3 : 6)) + (wi_ < 49 ? 0 : (wi_ < 53 ? 1 : 2));
#pragma unroll
      for (int ni = 0; ni < 4; ++ni) {
        float b = ptab[((ri - rj[ni] + 6) * 13 + (ci - cj[ni] + 6)) * 4 + h];
        float val = s[mi][ni][j] * SCALE_Q + b;
        if (cnti != cntj[ni]) val -= 100.0f;
        if (jbad[ni]) val = -1e30f;
        s[mi][ni][j] = val;
      }
    }

#pragma unroll
  for (int mi = 0; mi < 4; ++mi)
#pragma unroll
    for (int j = 0; j < 4; ++j) {
      float m = fmaxf(fmaxf(s[mi][0][j], s[mi][1][j]), fmaxf(s[mi][2][j], s[mi][3][j]));
#pragma unroll
      for (int off = 8; off; off >>= 1) m = fmaxf(m, __shfl_xor(m, off));
      float e[4], sum = 0.0f;
#pragma unroll
      for (int ni = 0; ni < 4; ++ni) { e[ni] = __expf(s[mi][ni][j] - m); sum += e[ni]; }
#pragma unroll
      for (int off = 8; off; off >>= 1) sum += __shfl_xor(sum, off);
      float inv = 1.0f / sum;
#pragma unroll
      for (int ni = 0; ni < 4; ++ni) s[mi][ni][j] = e[ni] * inv;
    }

#pragma unroll
  for (int mi = 0; mi < 4; ++mi)
#pragma unroll
    for (int j = 0; j < 4; ++j) {
      int row = mi * 16 + lg4 + j;
      int sw = (row & 7) << 4;
      char* prow = Pl + row * 128;
#pragma unroll
      for (int ni = 0; ni < 4; ++ni)
        *(__hip_bfloat16*)(prow + (((ni * 16 + lxi) * 2) ^ sw)) =
            __float2bfloat16(s[mi][ni][j]);
    }

  __syncthreads();

  f32x4 o[4][2] = {};
#pragma unroll
  for (int ks = 0; ks < 2; ++ks) {
    bf16x8 pa[4], vb[2];
#pragma unroll
    for (int mi = 0; mi < 4; ++mi) {
      int row = mi * 16 + lxi;
      pa[mi] = *(const bf16x8*)(Pl + row * 128 + ((ks * 64 + lq * 16) ^ ((row & 7) << 4)));
    }
#pragma unroll
    for (int ni = 0; ni < 2; ++ni) {
      int row = ni * 16 + lxi;
      vb[ni] = *(const bf16x8*)(VTl + row * 128 + ((ks * 64 + lq * 16) ^ ((row & 7) << 4)));
    }
#pragma unroll
    for (int mi = 0; mi < 4; ++mi)
#pragma unroll
      for (int ni = 0; ni < 2; ++ni)
        o[mi][ni] = __builtin_amdgcn_mfma_f32_16x16x32_bf16(pa[mi], vb[ni], o[mi][ni], 0, 0, 0);
  }

#pragma unroll
  for (int mi = 0; mi < 4; ++mi)
#pragma unroll
    for (int j = 0; j < 4; ++j) {
      int q = mi * 16 + lg4 + j;
      if (q < 49) {
#pragma unroll
        for (int ni = 0; ni < 2; ++ni)
          op[(size_t)q * 128 + ni * 16 + lxi] = __float2bfloat16(o[mi][ni][j]);
      }
    }
}

// ---------------------------------------------------------------------------
// MFMA bf16 GEMM: 128x128 tile, BK=128, A staged in LDS, B-fragments
// directly from global (weights L1/L2-resident). XCD-grouped 1D grid.
// EPI: 0 = +bias -> bf16 (ldo)
//      4 = proj+LN2 fused (NB==1): x2[tok]=bf16(acc+bias+resf[tok]);
//          out2[tok]=bf16(LN(row)*nw+nb)
// ---------------------------------------------------------------------------
template<int EPI>
__global__ __launch_bounds__(256) void gemm_mfma(
    const __hip_bfloat16* __restrict__ A, int lda, int NB,
    const __hip_bfloat16* __restrict__ Wt,
    const float* __restrict__ bias,
    void* __restrict__ outv, int ldo,
    __hip_bfloat16* __restrict__ out2,
    const float* __restrict__ nw, const float* __restrict__ nb,
    const float* __restrict__ resf, int K)
{
  __shared__ __align__(16) char AsB[128 * 256];
  __shared__ float redS[256], redQ[256];
  const int bid = blockIdx.x;
  const int xcd = bid & 7, tt = bid >> 3;
  const int nbk = tt % NB, mseq = tt / NB;
  const int m0 = (mseq * 8 + xcd) * 128, n0 = nbk * 128;
  const int tid = threadIdx.x;
  const int srow = tid >> 1;
  const int scol = (tid & 1) * 64;
  const int lane = tid & 63, wid = tid >> 6;
  const int wm = wid >> 1, wn = wid & 1;
  const int lrow = lane & 15, lq = lane >> 4;

  f32x4 acc[4][4] = {};

  for (int k0 = 0; k0 < K; k0 += 128) {
    {
      const char* ap = (const char*)A + ((size_t)(m0 + srow) * lda + k0 + scol) * 2;
      char* dst = AsB + srow * 256;
      int sw = (srow & 7) << 4;
#pragma unroll
      for (int t = 0; t < 8; ++t) {
        int4 raw = *(const int4*)(ap + t * 16);
        *(int4*)(dst + ((scol * 2 + t * 16) ^ sw)) = raw;
      }
    }
    __syncthreads();
#pragma unroll
    for (int ks = 0; ks < 4; ++ks) {
      int kb = ks * 64 + lq * 16;
      bf16x8 af[4], bfr[4];
#pragma unroll
      for (int mi = 0; mi < 4; ++mi) {
        int r = wm * 64 + mi * 16 + lrow;
        af[mi] = *(const bf16x8*)(AsB + r * 256 + (kb ^ ((r & 7) << 4)));
      }
#pragma unroll
      for (int ni = 0; ni < 4; ++ni) {
        int n = n0 + wn * 64 + ni * 16 + lrow;
        bfr[ni] = *(const bf16x8*)(Wt + (size_t)n * K + k0 + ks * 32 + lq * 8);
      }
#pragma unroll
      for (int mi = 0; mi < 4; ++mi)
#pragma unroll
        for (int ni = 0; ni < 4; ++ni)
          acc[mi][ni] = __builtin_amdgcn_mfma_f32_16x16x32_bf16(af[mi], bfr[ni], acc[mi][ni], 0, 0, 0);
    }
    __syncthreads();
  }

  float bv[4];
#pragma unroll
  for (int ni = 0; ni < 4; ++ni) bv[ni] = bias[n0 + wn * 64 + ni * 16 + lrow];

  if (EPI == 4) {
    // proj + residual + LN2 fused. NB == 1: block owns full 128-wide rows.
    __hip_bfloat16* x2 = (__hip_bfloat16*)outv;
    float nwc[4], nbc[4];
#pragma unroll
    for (int ni = 0; ni < 4; ++ni) {
      int colg = wn * 64 + ni * 16 + lrow;
      nwc[ni] = nw[colg]; nbc[ni] = nb[colg];
    }
    int toks[4][4];
#pragma unroll
    for (int mi = 0; mi < 4; ++mi)
#pragma unroll
      for (int j = 0; j < 4; ++j) {
        int row = wm * 64 + mi * 16 + lq * 4 + j;
        int tok = wt_to_tok(m0 + row);
        toks[mi][j] = tok;
        float s = 0.0f, ss = 0.0f;
#pragma unroll
        for (int ni = 0; ni < 4; ++ni) {
          int colg = wn * 64 + ni * 16 + lrow;
          float val = acc[mi][ni][j] + bv[ni] + resf[(size_t)tok * 128 + colg];
          x2[(size_t)tok * 128 + colg] = __float2bfloat16(val);
          acc[mi][ni][j] = val;
          s += val; ss += val * val;
        }
#pragma unroll
        for (int off = 8; off; off >>= 1) {
          s += __shfl_xor(s, off);
          ss += __shfl_xor(ss, off);
        }
        if (lrow == 0) { redS[row * 2 + wn] = s; redQ[row * 2 + wn] = ss; }
      }
    __syncthreads();
#pragma unroll
    for (int mi = 0; mi < 4; ++mi)
#pragma unroll
      for (int j = 0; j < 4; ++j) {
        int row = wm * 64 + mi * 16 + lq * 4 + j;
        float s = redS[row * 2] + redS[row * 2 + 1];
        float ss = redQ[row * 2] + redQ[row * 2 + 1];
        float mu = s * (1.0f / 128.0f);
        float rstd = rsqrtf(ss * (1.0f / 128.0f) - mu * mu + 1e-5f);
        int tok = toks[mi][j];
#pragma unroll
        for (int ni = 0; ni < 4; ++ni) {
          int colg = wn * 64 + ni * 16 + lrow;
          float xnv = (acc[mi][ni][j] - mu) * rstd * nwc[ni] + nbc[ni];
          out2[(size_t)tok * 128 + colg] = __float2bfloat16(xnv);
        }
      }
    return;
  }

#pragma unroll
  for (int mi = 0; mi < 4; ++mi) {
#pragma unroll
    for (int j = 0; j < 4; ++j) {
      int rowg = m0 + wm * 64 + mi * 16 + lq * 4 + j;
#pragma unroll
      for (int ni = 0; ni < 4; ++ni) {
        int colg = n0 + wn * 64 + ni * 16 + lrow;
        float val = acc[mi][ni][j] + bv[ni];
        ((__hip_bfloat16*)outv)[(size_t)rowg * ldo + colg] = __float2bfloat16(val);
      }
    }
  }
}

// ---------------------------------------------------------------------------
// Fused MLP (r6 structure — best measured): out = x2 + gelu(x2n@W1+b1)@W2+b2.
// 128 tokens/block, 4 hidden chunks of 128; hidden never touches HBM.
// gemm1 operand-swapped (D=[hd][m]) so gelu output packs to 8B LDS writes;
// W1/W2 B-fragments direct from global. gelu_sig (5 VALU) on the serial path.
// ---------------------------------------------------------------------------
__global__ __launch_bounds__(256) void mlp_fused(
    const __hip_bfloat16* __restrict__ x2n,  // [NTOK][128]
    const __hip_bfloat16* __restrict__ w1T,  // [512][128]
    const float* __restrict__ b1,
    const __hip_bfloat16* __restrict__ w2T,  // [128][512]
    const float* __restrict__ b2,
    const __hip_bfloat16* __restrict__ x2,   // [NTOK][128] residual
    float* __restrict__ out)                 // [NTOK][128]
{
  __shared__ __align__(16) char AsB[128 * 256];
  __shared__ __align__(16) char Hs[128 * 256];
  const int m0 = blockIdx.x * 128;
  const int tid = threadIdx.x;
  const int srow = tid >> 1, scol = (tid & 1) * 64;
  const int lane = tid & 63, wid = tid >> 6;
  const int wm = wid >> 1, wn = wid & 1;
  const int lrow = lane & 15, lq = lane >> 4;

  // stage A = x2n tile (swizzled)
  {
    const char* ap = (const char*)x2n + ((size_t)(m0 + srow) * 128 + scol) * 2;
    char* dst = AsB + srow * 256;
    int sw = (srow & 7) << 4;
#pragma unroll
    for (int t = 0; t < 8; ++t) {
      int4 raw = *(const int4*)(ap + t * 16);
      *(int4*)(dst + ((scol * 2 + t * 16) ^ sw)) = raw;
    }
  }
  __syncthreads();

  f32x4 oacc[4][4] = {};

  for (int c = 0; c < 4; ++c) {
    // ---- gemm1 (swapped): hT[hd][m] = W1c-rows x A-rows ----
    f32x4 hacc[4][4] = {};
#pragma unroll
    for (int ks = 0; ks < 4; ++ks) {
      int kb = ks * 64 + lq * 16;
      bf16x8 wf[4], afr[4];
#pragma unroll
      for (int mi = 0; mi < 4; ++mi) {
        int hd = c * 128 + wm * 64 + mi * 16 + lrow;
        wf[mi] = *(const bf16x8*)(w1T + (size_t)hd * 128 + ks * 32 + lq * 8);
      }
#pragma unroll
      for (int ni = 0; ni < 4; ++ni) {
        int r = wn * 64 + ni * 16 + lrow;
        afr[ni] = *(const bf16x8*)(AsB + r * 256 + (kb ^ ((r & 7) << 4)));
      }
#pragma unroll
      for (int mi = 0; mi < 4; ++mi)
#pragma unroll
        for (int ni = 0; ni < 4; ++ni)
          hacc[mi][ni] = __builtin_amdgcn_mfma_f32_16x16x32_bf16(wf[mi], afr[ni], hacc[mi][ni], 0, 0, 0);
    }
    __syncthreads();   // previous chunk's Hs fully consumed
    // gelu_sig(+b1), write h to Hs[m][hd_local] — 4 consecutive hd pack to 8B
#pragma unroll
    for (int mi = 0; mi < 4; ++mi) {
      int hdb = wm * 64 + mi * 16 + lq * 4;       // hd_local base (16B-aligned)
      float4 b4 = *(const float4*)(b1 + c * 128 + hdb);
      float b1v[4] = {b4.x, b4.y, b4.z, b4.w};
#pragma unroll
      for (int ni = 0; ni < 4; ++ni) {
        int m_ = wn * 64 + ni * 16 + lrow;
        bh4 hv;
        hv.a = __float2bfloat16(gelu_sig(hacc[mi][ni][0] + b1v[0]));
        hv.b = __float2bfloat16(gelu_sig(hacc[mi][ni][1] + b1v[1]));
        hv.c = __float2bfloat16(gelu_sig(hacc[mi][ni][2] + b1v[2]));
        hv.d = __float2bfloat16(gelu_sig(hacc[mi][ni][3] + b1v[3]));
        *(bh4*)(Hs + m_ * 256 + ((hdb * 2) ^ ((m_ & 7) << 4))) = hv;
      }
    }
    __syncthreads();
    // ---- gemm2: out += H @ W2c ----
#pragma unroll
    for (int ks = 0; ks < 4; ++ks) {
      int kb = ks * 64 + lq * 16;
      bf16x8 hf[4], w2f[4];
#pragma unroll
      for (int mi = 0; mi < 4; ++mi) {
        int r = wm * 64 + mi * 16 + lrow;
        hf[mi] = *(const bf16x8*)(Hs + r * 256 + (kb ^ ((r & 7) << 4)));
      }
#pragma unroll
      for (int ni = 0; ni < 4; ++ni) {
        int n = wn * 64 + ni * 16 + lrow;
        w2f[ni] = *(const bf16x8*)(w2T + (size_t)n * 512 + c * 128 + ks * 32 + lq * 8);
      }
#pragma unroll
      for (int mi = 0; mi < 4; ++mi)
#pragma unroll
        for (int ni = 0; ni < 4; ++ni)
          oacc[mi][ni] = __builtin_amdgcn_mfma_f32_16x16x32_bf16(hf[mi], w2f[ni], oacc[mi][ni], 0, 0, 0);
    }
  }

  // epilogue: + b2 + residual -> fp32 out
  float bv[4];
#pragma unroll
  for (int ni = 0; ni < 4; ++ni) bv[ni] = b2[wn * 64 + ni * 16 + lrow];
#pragma unroll
  for (int mi = 0; mi < 4; ++mi)
#pragma unroll
    for (int j = 0; j < 4; ++j) {
      int row = m0 + wm * 64 + mi * 16 + lq * 4 + j;
#pragma unroll
      for (int ni = 0; ni < 4; ++ni) {
        int col = wn * 64 + ni * 16 + lrow;
        float r = __bfloat162float(x2[(size_t)row * 128 + col]);
        out[(size_t)row * 128 + col] = oacc[mi][ni][j] + bv[ni] + r;
      }
    }
}

extern "C" void kernel_launch(void* const* d_in, const int* in_sizes, int n_in,
                              void* d_out, int out_size, void* d_ws, size_t ws_size,
                              hipStream_t stream) {
  (void)in_sizes; (void)n_in; (void)out_size; (void)ws_size;
  const float* x     = (const float*)d_in[0];
  const float* n1w   = (const float*)d_in[1];
  const float* n1b   = (const float*)d_in[2];
  const float* qkvw  = (const float*)d_in[3];
  const float* qkvb  = (const float*)d_in[4];
  const float* projw = (const float*)d_in[5];
  const float* projb = (const float*)d_in[6];
  const float* ptab  = (const float*)d_in[7];
  const float* w1    = (const float*)d_in[8];
  const float* b1    = (const float*)d_in[9];
  const float* w2    = (const float*)d_in[10];
  const float* b2    = (const float*)d_in[11];
  const float* n2w   = (const float*)d_in[12];
  const float* n2b   = (const float*)d_in[13];
  float* out = (float*)d_out;

  // workspace layout (bytes):
  //   [0,          25690112)   xn   bf16 [wt][128]  (LN1, window order)
  //   [25690112,  102760448)   qkv  bf16 [wt][384]
  //   [102760448, 128450560)   attnout bf16 [wt][128]
  //   [128450560, 154140672)   x2   bf16 [tok][128]  (residual stream)
  //   [154140672, 179830784)   x2n  bf16 [tok][128]  (LN2 applied)
  //   [179830784, 180224000)   transposed bf16 weights
  char* ws = (char*)d_ws;
  __hip_bfloat16* xn      = (__hip_bfloat16*)ws;
  __hip_bfloat16* qkv     = (__hip_bfloat16*)(ws + 25690112);
  __hip_bfloat16* attnout = (__hip_bfloat16*)(ws + 102760448);
  __hip_bfloat16* x2      = (__hip_bfloat16*)(ws + 128450560);
  __hip_bfloat16* x2n     = (__hip_bfloat16*)(ws + 154140672);
  __hip_bfloat16* wbase   = (__hip_bfloat16*)(ws + 179830784);
  __hip_bfloat16* qkvwT  = wbase;            // [384][128]
  __hip_bfloat16* projwT = wbase + 49152;    // [128][128]
  __hip_bfloat16* w1T    = wbase + 65536;    // [512][128]
  __hip_bfloat16* w2T    = wbase + 131072;   // [128][512]

  prep_all<<<768, 256, 0, stream>>>(qkvw, projw, w1, w2, wbase);
  ln1_apply<<<NTOK / 4, 256, 0, stream>>>(x, n1w, n1b, xn);
  // qkv = xn @ qkv_w + qkv_b  (bf16): NB=3 -> grid 2352
  gemm_mfma<0><<<2352, 256, 0, stream>>>(xn, 128, 3, qkvwT, qkvb,
                                         qkv, 384, nullptr, nullptr, nullptr,
                                         nullptr, 128);
  attn_mfma<<<2048, 256, 0, stream>>>(qkv, ptab, attnout);
  // x2[tok] = bf16(x[tok] + attnout @ proj_w + proj_b); x2n = bf16(LN2(row))
  gemm_mfma<4><<<784, 256, 0, stream>>>(attnout, 128, 1, projwT, projb,
                                        x2, 128, x2n, n2w, n2b, x, 128);
  // out = x2 + gelu(x2n @ w1 + b1) @ w2 + b2   (hidden never hits HBM)
  mlp_fused<<<784, 256, 0, stream>>>(x2n, w1T, b1, w2T, b2, x2, out);
}